// Round 12
// baseline (273.068 us; speedup 1.0000x reference)
//
#include <hip/hip_runtime.h>
#include <hip/hip_bf16.h>

#define NROW 8192
#define FINC 256
#define FOUTC 256
#define KSPLIT 8
#define KLOC (NROW / KSPLIT)   // 1024
#define KSTEPS (KLOC / 32)     // 32 k-steps of 32

typedef __attribute__((ext_vector_type(8))) short bf16x8;
typedef __attribute__((ext_vector_type(4))) float f32x4;

__device__ __forceinline__ unsigned short f2bf(float f) {
  unsigned u = __float_as_uint(f);
  u += 0x7fffu + ((u >> 16) & 1u);   // round-to-nearest-even
  return (unsigned short)(u >> 16);
}
__device__ __forceinline__ float bf2f(unsigned short h) {
  return __uint_as_float(((unsigned)h) << 16);
}
__device__ __forceinline__ bf16x8 pk8(float4 a, float4 b) {
  bf16x8 r;
  r[0] = (short)f2bf(a.x); r[1] = (short)f2bf(a.y);
  r[2] = (short)f2bf(a.z); r[3] = (short)f2bf(a.w);
  r[4] = (short)f2bf(b.x); r[5] = (short)f2bf(b.y);
  r[6] = (short)f2bf(b.z); r[7] = (short)f2bf(b.w);
  return r;
}

// ---- kernel 1: D[i] = 1/sqrt(1 + sum_j adj[i][j]); one wave per row ----
__global__ __launch_bounds__(256) void rowsum_kernel(const float* __restrict__ adj,
                                                     float* __restrict__ D) {
  const int row = blockIdx.x * 4 + (threadIdx.x >> 6);
  const int l = threadIdx.x & 63;
  const float4* p = reinterpret_cast<const float4*>(adj + (size_t)row * NROW);
  float s0 = 0.f, s1 = 0.f, s2 = 0.f, s3 = 0.f;
#pragma unroll
  for (int i = 0; i < 8; ++i) {
    float4 a = p[l + (i * 4 + 0) * 64];
    float4 b = p[l + (i * 4 + 1) * 64];
    float4 c = p[l + (i * 4 + 2) * 64];
    float4 d = p[l + (i * 4 + 3) * 64];
    s0 += (a.x + a.y) + (a.z + a.w);
    s1 += (b.x + b.y) + (b.z + b.w);
    s2 += (c.x + c.y) + (c.z + c.w);
    s3 += (d.x + d.y) + (d.z + d.w);
  }
  float s = (s0 + s1) + (s2 + s3);
#pragma unroll
  for (int off = 32; off > 0; off >>= 1) s += __shfl_down(s, off, 64);
  if (l == 0) D[row] = 1.0f / sqrtf(s + 1.0f);
}

// ---- kernel 2: s2T[f][j] = s2R[j][f] = bf16( D[j] * (x @ W)[j][f] ) ----
__global__ __launch_bounds__(256) void support_kernel(const float* __restrict__ x,
                                                      const float* __restrict__ W,
                                                      const float* __restrict__ D,
                                                      unsigned short* __restrict__ s2T,
                                                      unsigned short* __restrict__ s2R) {
  __shared__ float xs[32][FINC];
  const int t = threadIdx.x;
  const int r0 = blockIdx.x * 32;
  {
    const float4* xg = reinterpret_cast<const float4*>(x + (size_t)r0 * FINC);
    float4* xl = reinterpret_cast<float4*>(&xs[0][0]);
#pragma unroll
    for (int i = 0; i < 8; ++i) xl[t + i * 256] = xg[t + i * 256];
  }
  __syncthreads();
  const int w = t >> 6, l = t & 63;
  float acc[8][4] = {};
  const float4* W4 = reinterpret_cast<const float4*>(W);
#pragma unroll 4
  for (int k = 0; k < FINC; ++k) {
    float4 wv = W4[k * 64 + l];
#pragma unroll
    for (int m = 0; m < 8; ++m) {
      float xv = xs[w * 8 + m][k];
      acc[m][0] = fmaf(xv, wv.x, acc[m][0]);
      acc[m][1] = fmaf(xv, wv.y, acc[m][1]);
      acc[m][2] = fmaf(xv, wv.z, acc[m][2]);
      acc[m][3] = fmaf(xv, wv.w, acc[m][3]);
    }
  }
#pragma unroll
  for (int m = 0; m < 8; ++m) {
    const int j = r0 + w * 8 + m;
    const float d = D[j];
    const int f0 = l * 4;
    ushort4 rv;
    rv.x = f2bf(d * acc[m][0]);
    rv.y = f2bf(d * acc[m][1]);
    rv.z = f2bf(d * acc[m][2]);
    rv.w = f2bf(d * acc[m][3]);
    *reinterpret_cast<ushort4*>(&s2R[(size_t)j * FOUTC + f0]) = rv;
    s2T[(size_t)(f0 + 0) * NROW + j] = rv.x;
    s2T[(size_t)(f0 + 1) * NROW + j] = rv.y;
    s2T[(size_t)(f0 + 2) * NROW + j] = rv.z;
    s2T[(size_t)(f0 + 3) * NROW + j] = rv.w;
  }
}

// ---- kernel 3: wave-independent K-split GEMM. NO LDS, NO BARRIERS.
// Each wave: 32 adj rows x 256 f x K-slice (KLOC=1024). A: HBM->VGPR
// (2 coalesced float4 per row-tile per k-step, sequential within row).
// B: L2->VGPR, one 16-B load per f-tile per k-step (s2T rows contiguous in j).
// acc[2][16] (128 VGPR). ks = bid&7 == XCD -> 512 KB B-slice L2-resident.
// Waves fully independent (rowsum-like streaming); latency hidden by
// per-wave MLP (8-16 loads in flight) + 8 waves/CU, not by barrier pipelines.
__global__ __launch_bounds__(256, 2) void gcn_gemm_kernel(const float* __restrict__ adj,
                                                          const unsigned short* __restrict__ s2T,
                                                          float* __restrict__ part) {
  const int t = threadIdx.x, w = t >> 6, l = t & 63;
  const int bid = blockIdx.x;
  const int ks = bid & 7;                    // == XCD id (bid%8)
  const int s = (bid >> 3) * 4 + w;          // strip 0..255
  const int r0 = s * 32;
  const size_t k0 = (size_t)ks * KLOC;
  const int lr = l & 15;                     // A-row / B-f within tile
  const int kg = l >> 4;                     // k-group 0..3

  const float* ap0 = adj + (size_t)(r0 + lr) * NROW + k0 + kg * 8;
  const float* ap1 = ap0 + (size_t)16 * NROW;
  const unsigned short* bp = s2T + (size_t)lr * NROW + k0 + kg * 8;

  f32x4 acc[2][16] = {};

  // prologue: A(0)
  float4 ca0 = *reinterpret_cast<const float4*>(ap0);
  float4 ca1 = *reinterpret_cast<const float4*>(ap0 + 4);
  float4 ca2 = *reinterpret_cast<const float4*>(ap1);
  float4 ca3 = *reinterpret_cast<const float4*>(ap1 + 4);
  float4 na0, na1, na2, na3;

  // substep: consume CA* (step ST), prefetch NA* (step ST+1) between B halves
#define SUB(ST, CA0, CA1, CA2, CA3, NA0, NA1, NA2, NA3)                        \
  {                                                                            \
    const unsigned short* bq = bp + (size_t)(ST) * 32;                         \
    bf16x8 a0 = pk8(CA0, CA1);                                                 \
    bf16x8 a1 = pk8(CA2, CA3);                                                 \
    bf16x8 bf[8];                                                              \
    _Pragma("unroll")                                                          \
    for (int ft = 0; ft < 8; ++ft)                                             \
      bf[ft] = *reinterpret_cast<const bf16x8*>(bq + (size_t)ft * (16 * NROW));\
    if ((ST) + 1 < KSTEPS) {                                                   \
      NA0 = *reinterpret_cast<const float4*>(ap0 + ((ST) + 1) * 32);           \
      NA1 = *reinterpret_cast<const float4*>(ap0 + ((ST) + 1) * 32 + 4);       \
      NA2 = *reinterpret_cast<const float4*>(ap1 + ((ST) + 1) * 32);           \
      NA3 = *reinterpret_cast<const float4*>(ap1 + ((ST) + 1) * 32 + 4);       \
    }                                                                          \
    _Pragma("unroll")                                                          \
    for (int ft = 0; ft < 8; ++ft) {                                           \
      acc[0][ft] = __builtin_amdgcn_mfma_f32_16x16x32_bf16(a0, bf[ft],         \
                                                           acc[0][ft], 0, 0, 0);\
      acc[1][ft] = __builtin_amdgcn_mfma_f32_16x16x32_bf16(a1, bf[ft],         \
                                                           acc[1][ft], 0, 0, 0);\
    }                                                                          \
    _Pragma("unroll")                                                          \
    for (int ft = 0; ft < 8; ++ft)                                             \
      bf[ft] = *reinterpret_cast<const bf16x8*>(bq +                           \
                                                (size_t)(ft + 8) * (16 * NROW));\
    _Pragma("unroll")                                                          \
    for (int ft = 0; ft < 8; ++ft) {                                           \
      acc[0][ft + 8] = __builtin_amdgcn_mfma_f32_16x16x32_bf16(a0, bf[ft],     \
                                                       acc[0][ft + 8], 0, 0, 0);\
      acc[1][ft + 8] = __builtin_amdgcn_mfma_f32_16x16x32_bf16(a1, bf[ft],     \
                                                       acc[1][ft + 8], 0, 0, 0);\
    }                                                                          \
  }

#pragma unroll 1
  for (int st = 0; st < KSTEPS; st += 2) {
    SUB(st + 0, ca0, ca1, ca2, ca3, na0, na1, na2, na3)
    SUB(st + 1, na0, na1, na2, na3, ca0, ca1, ca2, ca3)
  }
#undef SUB

  // epilogue: f32 partials; C/D layout col = l&15, row = (l>>4)*4 + q
  float* pout = part + (size_t)ks * NROW * FOUTC + (size_t)r0 * FOUTC;
#pragma unroll
  for (int rt = 0; rt < 2; ++rt) {
#pragma unroll
    for (int ft = 0; ft < 16; ++ft) {
#pragma unroll
      for (int q = 0; q < 4; ++q) {
        const int i = rt * 16 + kg * 4 + q;
        const int f = ft * 16 + lr;
        pout[(size_t)i * FOUTC + f] = acc[rt][ft][q];
      }
    }
  }
}

// ---- kernel 4: out[i][f] = relu( (sum_ks part + s2R[i][f]) * D[i] + b[f] ) ----
__global__ __launch_bounds__(256) void combine_kernel(const float* __restrict__ part,
                                                      const unsigned short* __restrict__ s2R,
                                                      const float* __restrict__ D,
                                                      const float* __restrict__ bias,
                                                      float* __restrict__ out) {
  const int idx = blockIdx.x * 256 + threadIdx.x;   // one float4 per thread
  const int i = idx >> 6;
  const int f0 = (idx & 63) * 4;
  const size_t off = (size_t)i * FOUTC + f0;
  const size_t stride = (size_t)NROW * FOUTC;
  float4 s = *reinterpret_cast<const float4*>(part + off);
#pragma unroll
  for (int ks = 1; ks < KSPLIT; ++ks) {
    float4 p = *reinterpret_cast<const float4*>(part + (size_t)ks * stride + off);
    s.x += p.x; s.y += p.y; s.z += p.z; s.w += p.w;
  }
  ushort4 sv = *reinterpret_cast<const ushort4*>(s2R + off);
  float di = D[i];
  float4 bv = *reinterpret_cast<const float4*>(bias + f0);
  float4 o;
  o.x = fmaxf((s.x + bf2f(sv.x)) * di + bv.x, 0.f);
  o.y = fmaxf((s.y + bf2f(sv.y)) * di + bv.y, 0.f);
  o.z = fmaxf((s.z + bf2f(sv.z)) * di + bv.z, 0.f);
  o.w = fmaxf((s.w + bf2f(sv.w)) * di + bv.w, 0.f);
  *reinterpret_cast<float4*>(out + off) = o;
}

// ================= fallback path (round-3, used if ws too small) =============
__global__ __launch_bounds__(512) void gemm_fb(const float* __restrict__ adj,
                                               const unsigned short* __restrict__ s2T,
                                               const float* __restrict__ D,
                                               const float* __restrict__ bias,
                                               float* __restrict__ out) {
  __shared__ __align__(16) unsigned short Asf[3][32 * 64];
  __shared__ __align__(16) unsigned short Bsf[3][FOUTC * 64];
  const int t = threadIdx.x, wid = t >> 6, l = t & 63;
  const int bm0 = blockIdx.x * 32;
  const int ar = t >> 4;
  const unsigned awoff = (unsigned)(ar * 128 + (((t & 15) * 8) ^ ((ar & 7) << 4)));
  const float4* arow = reinterpret_cast<const float4*>(adj + (size_t)(bm0 + ar) * NROW) + (t & 15);
  const int bn = l >> 3;
  const unsigned bks = (unsigned)(((l & 7) * 16) ^ (bn << 4));
  f32x4 acc[2][2] = {};
  const unsigned swz = (unsigned)((l & 7) << 4);
  const int fr = l & 15;
  const unsigned kb = (unsigned)((l >> 4) * 16);
  const int nb = wid * 32;
  const int NTF = NROW / 64;
  auto stageB = [&](int kt, int sl) {
#pragma unroll
    for (int i = 0; i < 4; ++i) {
      const int c = wid * 4 + i;
      const int n = c * 8 + bn;
      const unsigned short* src = s2T + (size_t)n * NROW + (size_t)kt * 64;
      __builtin_amdgcn_global_load_lds(
          (const __attribute__((address_space(1))) unsigned int*)((const char*)src + bks),
          (__attribute__((address_space(3))) unsigned int*)((char*)&Bsf[sl][0] + c * 1024),
          16, 0, 0);
    }
  };
  auto writeA = [&](float4 av, int sl) {
    ushort4 ab;
    ab.x = f2bf(av.x); ab.y = f2bf(av.y); ab.z = f2bf(av.z); ab.w = f2bf(av.w);
    *reinterpret_cast<ushort4*>((char*)&Asf[sl][0] + awoff) = ab;
  };
  auto compute = [&](int sl) {
    const char* Ab = (const char*)&Asf[sl][0];
    const char* Bb = (const char*)&Bsf[sl][0];
#pragma unroll
    for (int kk = 0; kk < 2; ++kk) {
      const unsigned kx = ((unsigned)(kk * 64) + kb) ^ swz;
      bf16x8 a0 = *reinterpret_cast<const bf16x8*>(Ab + fr * 128 + kx);
      bf16x8 a1 = *reinterpret_cast<const bf16x8*>(Ab + (fr + 16) * 128 + kx);
      bf16x8 b0 = *reinterpret_cast<const bf16x8*>(Bb + (nb + fr) * 128 + kx);
      bf16x8 b1 = *reinterpret_cast<const bf16x8*>(Bb + (nb + 16 + fr) * 128 + kx);
      acc[0][0] = __builtin_amdgcn_mfma_f32_16x16x32_bf16(a0, b0, acc[0][0], 0, 0, 0);
      acc[0][1] = __builtin_amdgcn_mfma_f32_16x16x32_bf16(a0, b1, acc[0][1], 0, 0, 0);
      acc[1][0] = __builtin_amdgcn_mfma_f32_16x16x32_bf16(a1, b0, acc[1][0], 0, 0, 0);
      acc[1][1] = __builtin_amdgcn_mfma_f32_16x16x32_bf16(a1, b1, acc[1][1], 0, 0, 0);
    }
  };
  float4 a0p, a1p, a2p;
  {
    float4 a0v = arow[0];
    asm volatile("" ::: "memory");
    stageB(0, 0);
    a1p = arow[16];
    asm volatile("" ::: "memory");
    stageB(1, 1);
    a2p = arow[32];
    asm volatile("s_waitcnt vmcnt(10)" ::: "memory");
    writeA(a0v, 0);
  }
#define PIPE_ITER(KT, S0, S1, S2, AW, AN)                                      \
  asm volatile("s_waitcnt vmcnt(5) lgkmcnt(0)\n\ts_barrier" ::: "memory");     \
  writeA(AW, S1);                                                              \
  stageB((KT) + 2, S2);                                                        \
  if ((KT) < NTF - 3) AN = arow[((KT) + 3) * 16];                              \
  compute(S0);
#pragma unroll 1
  for (int kt = 0; kt < NTF - 2; kt += 3) {
    PIPE_ITER(kt + 0, 0, 1, 2, a1p, a0p)
    PIPE_ITER(kt + 1, 1, 2, 0, a2p, a1p)
    PIPE_ITER(kt + 2, 2, 0, 1, a0p, a2p)
  }
#undef PIPE_ITER
  asm volatile("s_waitcnt vmcnt(4) lgkmcnt(0)\n\ts_barrier" ::: "memory");
  writeA(a1p, 1);
  compute(0);
  asm volatile("s_waitcnt vmcnt(0) lgkmcnt(0)\n\ts_barrier" ::: "memory");
  compute(1);
#pragma unroll
  for (int m = 0; m < 2; ++m) {
#pragma unroll
    for (int n = 0; n < 2; ++n) {
#pragma unroll
      for (int q = 0; q < 4; ++q) {
        const int i = bm0 + m * 16 + (l >> 4) * 4 + q;
        const int f = wid * 32 + n * 16 + fr;
        const float selfv = bf2f(s2T[(size_t)f * NROW + i]);
        float v = (acc[m][n][q] + selfv) * D[i] + bias[f];
        out[(size_t)i * FOUTC + f] = fmaxf(v, 0.0f);
      }
    }
  }
}

extern "C" void kernel_launch(void* const* d_in, const int* in_sizes, int n_in,
                              void* d_out, int out_size, void* d_ws, size_t ws_size,
                              hipStream_t stream) {
  const float* x   = (const float*)d_in[0];
  const float* adj = (const float*)d_in[1];
  const float* W   = (const float*)d_in[2];
  const float* b   = (const float*)d_in[3];
  float* out = (float*)d_out;

  char* wsb = (char*)d_ws;
  float* D            = (float*)wsb;                                   // 32 KB
  unsigned short* s2T = (unsigned short*)(wsb + 32768);                // 4 MB [f][j]
  unsigned short* s2R = (unsigned short*)(wsb + 32768 + (1u << 22));   // 4 MB [j][f]
  float* part         = (float*)(wsb + 32768 + (2u << 22));            // 64 MB

  const size_t need = 32768ull + (2ull << 22) + (size_t)KSPLIT * NROW * FOUTC * 4ull;
  rowsum_kernel<<<NROW / 4, 256, 0, stream>>>(adj, D);
  support_kernel<<<NROW / 32, 256, 0, stream>>>(x, W, D, s2T, s2R);
  if (ws_size >= need) {
    gcn_gemm_kernel<<<(NROW / 32 / 4) * KSPLIT, 256, 0, stream>>>(adj, s2T, part);
    combine_kernel<<<NROW * FOUTC / 1024, 256, 0, stream>>>(part, s2R, D, b, out);
  } else {
    gemm_fb<<<NROW / 32, 512, 0, stream>>>(adj, s2T, D, b, out);
  }
}